// Round 6
// baseline (421.266 us; speedup 1.0000x reference)
//
#include <hip/hip_runtime.h>
#include <stdint.h>

typedef unsigned long long u64;
typedef short v8s __attribute__((ext_vector_type(8)));   // 8 bf16 (4 VGPRs) — MFMA A/B frag
typedef float v4f __attribute__((ext_vector_type(4)));   // MFMA C/D frag

__device__ __forceinline__ unsigned short f2bf_rne(float f) {
  union { float f; unsigned u; } c; c.f = f;
  unsigned u = c.u;
  u += 0x7fffu + ((u >> 16) & 1u);   // round-to-nearest-even
  return (unsigned short)(u >> 16);
}

// unpack two bf16x4 vectors, accumulate S[k] += z[k] - a[k] (8 couts)
__device__ __forceinline__ void bacc(uint4 z, uint4 a, float* S) {
  const unsigned* zp = &z.x;
  const unsigned* ap = &a.x;
  #pragma unroll
  for (int k = 0; k < 4; k++) {
    unsigned zu = zp[k], au = ap[k];
    float zl = __uint_as_float(zu << 16);
    float zh = __uint_as_float(zu & 0xffff0000u);
    float al = __uint_as_float(au << 16);
    float ah = __uint_as_float(au & 0xffff0000u);
    S[2 * k]     += zl - al;
    S[2 * k + 1] += zh - ah;
  }
}

// Pre-pack conv2 weights to bf16, split-K layout:
// Wr[h*25600 + c*800 + tap*32 + chh] = w2[c][h*32+chh][tap]
__global__ __launch_bounds__(256) void prepack_w2(
    const float* __restrict__ w2, unsigned short* __restrict__ Wr) {
  int idx = blockIdx.x * 256 + threadIdx.x;
  if (idx >= 32 * 1600) return;
  int c = idx / 1600, rem = idx - c * 1600;
  int h = rem / 800, r2 = rem - h * 800;
  int tap = r2 >> 5, chh = r2 & 31;
  Wr[h * 25600 + c * 800 + r2] = f2bf_rne(w2[(c * 64 + h * 32 + chh) * 25 + tap]);
}

// One block (512 thr = 8 waves) per image, fully fused incl. fc.
// LDS map (dynamic, 77280 B -> 2 blocks/CU):
//   Xs @0:      bf16[900 pix][36 shorts], pixel stride 72 B (validated r5:
//               phase-3 b64 fragments conflict-free, SQ_LDS_BANK_CONFLICT
//               3.55e7 -> 2.6e6).
//   P  @64800:  bf16[2 cin][6 rows][2 dx][30 qx][8 cout]  (11520 B).
//               Row 0 = 0 -> pooled value = P[zr]-P[ar] with NO flags;
//               one b128 = all 8 couts; consecutive-lane stride 16 B.
//   partial @76320 (832 B), fs @77152 (128 B). Cout aliases Xs in phase 4.
__global__ __launch_bounds__(512, 4) void fused_kernel(
    const float* __restrict__ bboxes,   // [16][32][4]
    const int*   __restrict__ pairs,    // [16][64][2]
    const float* __restrict__ w1,       // [64][2][5][5]
    const float* __restrict__ b1,       // [64]
    const unsigned short* __restrict__ Wr, // [2][32][800] bf16
    const float* __restrict__ b2,       // [32]
    const float* __restrict__ fcw,      // [512][32]
    const float* __restrict__ fcb,      // [512]
    float* __restrict__ out)            // [1024][512]
{
  extern __shared__ char smem[];
  unsigned short* Psh = (unsigned short*)(smem + 64800);
  float* partial = (float*)(smem + 76320);
  float* fs      = (float*)(smem + 77152);
  float* Cout    = (float*)smem;

  const int n = blockIdx.x, t = threadIdx.x;
  const int lane = t & 63, wv = t >> 6;
  const int q = lane >> 4, ln = lane & 15;

  // ---- phase 1: box pair -> indicator bitmasks (lane = coordinate) ----
  const int bb = n >> 6, rr_ = n & 63;
  const int p0 = pairs[(bb * 64 + rr_) * 2 + 0];
  const int p1 = pairs[(bb * 64 + rr_) * 2 + 1];
  const float* A  = bboxes + (bb * 32 + p0) * 4;
  const float* Bq = bboxes + (bb * 32 + p1) * 4;
  const float ax1 = A[0],  ay1 = A[1],  ax2 = A[2],  ay2 = A[3];
  const float cx1 = Bq[0], cy1 = Bq[1], cx2 = Bq[2], cy2 = Bq[3];
  const float ux1 = fminf(ax1, cx1), uy1 = fminf(ay1, cy1);
  const float ux2 = fmaxf(ax2, cx2), uy2 = fmaxf(ay2, cy2);
  const float uw = fmaxf(ux2 - ux1, 1e-6f), uh = fmaxf(uy2 - uy1, 1e-6f);
  const float g = (float)lane + 0.5f;
  u64 ixs[2], iys[2];
  {
    float X1 = (ax1 - ux1) / uw * 64.f, X2 = (ax2 - ux1) / uw * 64.f;
    float Y1 = (ay1 - uy1) / uh * 64.f, Y2 = (ay2 - uy1) / uh * 64.f;
    ixs[0] = __ballot(g >= X1 && g <= X2);
    iys[0] = __ballot(g >= Y1 && g <= Y2);
  }
  {
    float X1 = (cx1 - ux1) / uw * 64.f, X2 = (cx2 - ux1) / uw * 64.f;
    float Y1 = (cy1 - uy1) / uh * 64.f, Y2 = (cy2 - uy1) / uh * 64.f;
    ixs[1] = __ballot(g >= X1 && g <= X2);
    iys[1] = __ballot(g >= Y1 && g <= Y2);
  }

  // ---- hoisted per-pixel gather descriptors (chunk-independent) ----
  // P byte offsets: ch*5760 + row*960 (+480 for dx=1) + qx*16
  int pb_[2];                 // P base byte offset + qx*16
  int zo_[2][2][2], ao_[2][2][2];   // [pp][ch][dy]
  #pragma unroll
  for (int pp = 0; pp < 2; pp++) {
    int pix = t + pp * 512;
    bool vld = pix < 900;
    int qy = vld ? pix / 30 : 0;
    int qx = vld ? pix - qy * 30 : 0;
    pb_[pp] = 64800 + qx * 16;
    #pragma unroll
    for (int ch = 0; ch < 2; ch++) {
      #pragma unroll
      for (int dy = 0; dy < 2; dy++) {
        unsigned m = (unsigned)(iys[ch] >> (2 * qy + dy)) & 31u;
        int zr = 32 - __clz((int)m);          // 0 when m==0 -> zero row
        int ar = __ffs((int)m) - 1; if (ar < 0) ar = 0;
        zo_[pp][ch][dy] = ch * 5760 + zr * 960;
        ao_[pp][ch][dy] = ch * 5760 + ar * 960;
      }
    }
  }

  // ---- conv2 MFMA job setup (n-tiles of 16 pixels, 43 tiles) ----
  v4f acc[6][2];
  int pclamp[6], baseB[6];
  int cnt = 0;
  #pragma unroll
  for (int it = 0; it < 6; it++) {
    int nt = wv + it * 8;
    if (nt < 43) {
      int p = nt * 16 + ln; if (p > 675) p = 675;   // dup-compute pad lanes
      pclamp[it] = p;
      int y = p / 26, x = p - y * 26;
      baseB[it] = (y * 30 + x) * 72 + q * 16;
      cnt = it + 1;
    } else { pclamp[it] = 0; baseB[it] = 0; }
    acc[it][0] = (v4f)0.f; acc[it][1] = (v4f)0.f;
  }

  // ---- split-K passes over input-channel halves ----
  for (int h = 0; h < 2; h++) {
    // phase 2: conv1(+pool) for 32 out channels -> Xs, 4 chunks of 8 couts
    for (int c8 = 0; c8 < 4; c8++) {
      const int cbase = h * 32 + c8 * 8;
      // 2a) bf16 prefix tables, rows 0..5 (row 0 = zeros)
      for (int e = t; e < 960; e += 512) {
        int ch = e >= 480;
        int rem = e - ch * 480;
        int x = rem >> 3, cout = rem & 7;
        unsigned bits = (unsigned)(ixs[ch] >> x) & 31u;
        const float* wr = w1 + (cbase + cout) * 50 + ch * 25;
        int idx0 = ch * 2880 + (x & 1) * 240 + (x >> 1) * 8 + cout;
        Psh[idx0] = 0;
        float p = 0.f;
        #pragma unroll
        for (int i = 0; i < 5; i++) {
          float rcv = 0.f;
          #pragma unroll
          for (int j = 0; j < 5; j++)
            rcv += ((bits >> j) & 1u) ? wr[i * 5 + j] : 0.f;
          p += rcv;
          Psh[idx0 + (i + 1) * 480] = f2bf_rne(p);
        }
      }
      __syncthreads();   // P ready; also fences prior phase-3 Xs reads
      // 2b) pooled conv1 outputs -> Xs bf16: 16 unconditional b128 gathers
      float b1v[8];
      #pragma unroll
      for (int i = 0; i < 8; i++) b1v[i] = b1[cbase + i];
      #pragma unroll
      for (int pp = 0; pp < 2; pp++) {
        int pix = t + pp * 512;
        if (pix < 900) {
          const int pb = pb_[pp];
          float V[8];
          #pragma unroll
          for (int dy = 0; dy < 2; dy++) {
            float S0[8] = {0,0,0,0,0,0,0,0};
            float S1[8] = {0,0,0,0,0,0,0,0};
            #pragma unroll
            for (int ch = 0; ch < 2; ch++) {
              int zb = pb + zo_[pp][ch][dy];
              int ab = pb + ao_[pp][ch][dy];
              uint4 z0 = *(const uint4*)(smem + zb);
              uint4 a0 = *(const uint4*)(smem + ab);
              uint4 z1 = *(const uint4*)(smem + zb + 480);
              uint4 a1 = *(const uint4*)(smem + ab + 480);
              bacc(z0, a0, S0);
              bacc(z1, a1, S1);
            }
            #pragma unroll
            for (int k = 0; k < 8; k++) {
              float m = fmaxf(S0[k], S1[k]);
              V[k] = dy ? fmaxf(V[k], m) : m;
            }
          }
          unsigned dws[4];
          #pragma unroll
          for (int k = 0; k < 4; k++) {
            unsigned lo = (unsigned)f2bf_rne(V[2 * k]     + b1v[2 * k]);
            unsigned hi = (unsigned)f2bf_rne(V[2 * k + 1] + b1v[2 * k + 1]);
            dws[k] = lo | (hi << 16);
          }
          uint2 s0; s0.x = dws[0]; s0.y = dws[1];
          uint2 s1; s1.x = dws[2]; s1.y = dws[3];
          *(uint2*)(smem + pix * 72 + c8 * 16) = s0;
          *(uint2*)(smem + pix * 72 + c8 * 16 + 8) = s1;
        }
      }
      __syncthreads();
    }

    // phase 3: conv2 implicit-GEMM, K-half = 25 taps x 32 ch (25 s-steps)
    const unsigned short* pA0 = Wr + h * 25600 + ln * 800 + q * 8;
    const unsigned short* pA1 = pA0 + 16 * 800;
    for (int i = 0; i < 5; i++) {
      const int rowoff = i * 2160;            // i*30*72 bytes
      #pragma unroll
      for (int jt = 0; jt < 5; jt++) {
        const int s = i * 5 + jt;
        v8s a0 = *(const v8s*)(pA0 + s * 32);
        v8s a1 = *(const v8s*)(pA1 + s * 32);
        const int off = rowoff + jt * 72;
        #pragma unroll
        for (int it = 0; it < 6; it++) {
          if (it < cnt) {
            uint2 lo = *(const uint2*)(smem + (baseB[it] + off));
            uint2 hi = *(const uint2*)(smem + (baseB[it] + off + 8));
            uint4 bv; bv.x = lo.x; bv.y = lo.y; bv.z = hi.x; bv.w = hi.y;
            v8s b = __builtin_bit_cast(v8s, bv);
            acc[it][0] = __builtin_amdgcn_mfma_f32_16x16x32_bf16(a0, b, acc[it][0], 0, 0, 0);
            acc[it][1] = __builtin_amdgcn_mfma_f32_16x16x32_bf16(a1, b, acc[it][1], 0, 0, 0);
          }
        }
      }
    }
  }

  // ---- phase 4: per m-half, pool2 + mean + bias -> fs[32] (LDS) ----
  #pragma unroll
  for (int mt = 0; mt < 2; mt++) {
    __syncthreads();               // prior Xs/Cout readers done
    #pragma unroll
    for (int it = 0; it < 6; it++) {
      if (it < cnt) {
        #pragma unroll
        for (int r = 0; r < 4; r++)
          Cout[(q * 4 + r) * 677 + pclamp[it]] = acc[it][mt][r];
      }
    }
    __syncthreads();
    if (t < 208) {
      int c = t & 15, py = t >> 4;
      const float* r0 = Cout + c * 677 + (2 * py) * 26;
      const float* r1 = r0 + 26;
      float s = 0.f;
      #pragma unroll
      for (int px = 0; px < 13; px++) {
        float m0 = fmaxf(r0[2 * px], r0[2 * px + 1]);
        float m1 = fmaxf(r1[2 * px], r1[2 * px + 1]);
        s += fmaxf(m0, m1);
      }
      partial[t] = s;
    }
    __syncthreads();
    if (t < 16) {
      float s = 0.f;
      #pragma unroll
      for (int k = 0; k < 13; k++) s += partial[k * 16 + t];
      fs[mt * 16 + t] = s * (1.f / 169.f) + b2[mt * 16 + t];
    }
  }
  __syncthreads();

  // ---- phase 5: fc (512 outs, thread t -> out column t), relu ----
  {
    const float* wrow = fcw + t * 32;
    float d = 0.f;
    #pragma unroll
    for (int k = 0; k < 32; k++) d += wrow[k] * fs[k];
    out[(u64)n * 512 + t] = fmaxf(d + fcb[t], 0.f);
  }
}

extern "C" void kernel_launch(void* const* d_in, const int* in_sizes, int n_in,
                              void* d_out, int out_size, void* d_ws, size_t ws_size,
                              hipStream_t stream) {
  const float* bboxes = (const float*)d_in[0];
  // d_in[1] = num_obj, d_in[2] = num_relation: constants, unused by the math
  const int*   pairs  = (const int*)  d_in[3];
  const float* w1     = (const float*)d_in[4];
  const float* b1     = (const float*)d_in[5];
  const float* w2     = (const float*)d_in[6];
  const float* b2     = (const float*)d_in[7];
  const float* fcw    = (const float*)d_in[8];
  const float* fcb    = (const float*)d_in[9];
  float* out = (float*)d_out;

  unsigned short* Wr = (unsigned short*)d_ws;   // 102400 B

  prepack_w2<<<(32 * 1600 + 255) / 256, 256, 0, stream>>>(w2, Wr);
  fused_kernel<<<1024, 512, 77280, stream>>>(bboxes, pairs, w1, b1, Wr, b2,
                                             fcw, fcb, out);
}

// Round 7
// 409.438 us; speedup vs baseline: 1.0289x; 1.0289x over previous
//
#include <hip/hip_runtime.h>
#include <stdint.h>

typedef unsigned long long u64;
typedef short v8s __attribute__((ext_vector_type(8)));   // 8 bf16 (4 VGPRs) — MFMA A/B frag
typedef float v4f __attribute__((ext_vector_type(4)));   // MFMA C/D frag

__device__ __forceinline__ unsigned short f2bf_rne(float f) {
  union { float f; unsigned u; } c; c.f = f;
  unsigned u = c.u;
  u += 0x7fffu + ((u >> 16) & 1u);   // round-to-nearest-even
  return (unsigned short)(u >> 16);
}

// unpack bf16x8 pair (z,a), accumulate S[k] += z[k] - a[k]
__device__ __forceinline__ void bacc(uint4 z, uint4 a, float* S) {
  const unsigned* zp = &z.x;
  const unsigned* ap = &a.x;
  #pragma unroll
  for (int k = 0; k < 4; k++) {
    unsigned zu = zp[k], au = ap[k];
    S[2 * k]     += __uint_as_float(zu << 16)         - __uint_as_float(au << 16);
    S[2 * k + 1] += __uint_as_float(zu & 0xffff0000u) - __uint_as_float(au & 0xffff0000u);
  }
}

// Prepack: (a) conv2 weights bf16, k = tap*64+ch order (51200 entries);
// (b) conv1 closed-form LUT G[ch][cls][j][cout] (12288 entries, bf16):
//     for row-run class cls=(ia,ib) (0=empty), G = sum_{i=ia..ib} sum_{jj<j} w1.
//     Image-independent! conv1 rect-sum = G[cls][jb+1] - G[cls][ja].
__global__ __launch_bounds__(256) void prepack(
    const float* __restrict__ w1, const float* __restrict__ w2,
    unsigned short* __restrict__ Wr, unsigned short* __restrict__ Gt) {
  int idx = blockIdx.x * 256 + threadIdx.x;
  if (idx < 51200) {
    int c = idx / 1600, rem = idx - c * 1600;
    int ch = rem & 63, tap = rem >> 6;
    Wr[idx] = f2bf_rne(w2[(c * 64 + ch) * 25 + tap]);
  } else if (idx < 51200 + 12288) {
    int e = idx - 51200;
    int ch = e / 6144, r = e - ch * 6144;
    int cls = r / 384, r2 = r - cls * 384;
    int j = r2 / 64, cout = r2 - j * 64;
    float v = 0.f;
    if (cls > 0) {
      int ia = 0, ib = 0;
      for (int bb = 0; bb < 5; bb++) {
        int base = (bb * (bb + 1)) / 2 + 1;
        if (cls >= base && cls <= base + bb) { ib = bb; ia = cls - base; }
      }
      for (int i = ia; i <= ib; i++)
        for (int jj = 0; jj < j; jj++)
          v += w1[(cout * 2 + ch) * 25 + i * 5 + jj];
    }
    Gt[e] = f2bf_rne(v);
  }
}

// One block (512 thr = 8 waves) per image, fully fused, minimal barriers.
// LDS (dynamic 147936 B -> 1 block/CU):
//   Xs @0:      bf16[900 pix][68 shorts], stride 136 B. Phase-3 b64 fragment
//               reads: 16 same-q lanes hit even banks 2*ln -> each b64 covers
//               {2ln,2ln+1}: all 32 banks, conflict-free (validated r5).
//   G  @122400: bf16[2 ch][16 cls][6 j][64 cout] (24576 B). Class stride 768,
//               col stride 128 -> both ≡ 0 mod 128 B; 8 lanes (one pixel,
//               cg 0..7) read consecutive 16 B => every b128 phase tiles all
//               32 banks once: conflict-free for ANY data-dependent class.
//   partial @146976, fs @147808. Cout (32x677 f32 = 86656 B) aliases Xs.
__global__ __launch_bounds__(512, 2) void fused_kernel(
    const float* __restrict__ bboxes,   // [16][32][4]
    const int*   __restrict__ pairs,    // [16][64][2]
    const unsigned short* __restrict__ Gt, // [12288] bf16 LUT
    const float* __restrict__ b1,       // [64]
    const unsigned short* __restrict__ Wr, // [32][1600] bf16
    const float* __restrict__ b2,       // [32]
    const float* __restrict__ fcw,      // [512][32]
    const float* __restrict__ fcb,      // [512]
    float* __restrict__ out)            // [1024][512]
{
  extern __shared__ char smem[];
  float* partial = (float*)(smem + 146976);
  float* fs      = (float*)(smem + 147808);
  float* Cout    = (float*)smem;

  const int n = blockIdx.x, t = threadIdx.x;
  const int lane = t & 63, wv = t >> 6;
  const int q = lane >> 4, ln = lane & 15;

  // ---- G LUT -> LDS (1536 uint4, 3 per thread) ----
  {
    const uint4* src = (const uint4*)Gt;
    uint4* dst = (uint4*)(smem + 122400);
    #pragma unroll
    for (int i = 0; i < 3; i++) dst[t + i * 512] = src[t + i * 512];
  }

  // ---- phase 1: box pair -> indicator bitmasks (lane = coordinate) ----
  const int bb = n >> 6, rr_ = n & 63;
  const int p0 = pairs[(bb * 64 + rr_) * 2 + 0];
  const int p1 = pairs[(bb * 64 + rr_) * 2 + 1];
  const float* A  = bboxes + (bb * 32 + p0) * 4;
  const float* Bq = bboxes + (bb * 32 + p1) * 4;
  const float ax1 = A[0],  ay1 = A[1],  ax2 = A[2],  ay2 = A[3];
  const float cx1 = Bq[0], cy1 = Bq[1], cx2 = Bq[2], cy2 = Bq[3];
  const float ux1 = fminf(ax1, cx1), uy1 = fminf(ay1, cy1);
  const float ux2 = fmaxf(ax2, cx2), uy2 = fmaxf(ay2, cy2);
  const float uw = fmaxf(ux2 - ux1, 1e-6f), uh = fmaxf(uy2 - uy1, 1e-6f);
  const float g = (float)lane + 0.5f;
  u64 ixs[2], iys[2];
  {
    float X1 = (ax1 - ux1) / uw * 64.f, X2 = (ax2 - ux1) / uw * 64.f;
    float Y1 = (ay1 - uy1) / uh * 64.f, Y2 = (ay2 - uy1) / uh * 64.f;
    ixs[0] = __ballot(g >= X1 && g <= X2);
    iys[0] = __ballot(g >= Y1 && g <= Y2);
  }
  {
    float X1 = (cx1 - ux1) / uw * 64.f, X2 = (cx2 - ux1) / uw * 64.f;
    float Y1 = (cy1 - uy1) / uh * 64.f, Y2 = (cy2 - uy1) / uh * 64.f;
    ixs[1] = __ballot(g >= X1 && g <= X2);
    iys[1] = __ballot(g >= Y1 && g <= Y2);
  }
  __syncthreads();   // G resident

  // ---- phase 2: conv1+pool via G-LUT -> Xs. No barriers inside. ----
  // thread -> (pixel = t>>3 + 64*pass, cout-group cg = t&7), 15 passes.
  {
    const int cg = t & 7, cgo = cg * 16, pr = t >> 3;
    float b1v[8];
    #pragma unroll
    for (int i = 0; i < 8; i++) b1v[i] = b1[cg * 8 + i];
    for (int pass = 0; pass < 15; pass++) {
      int pix = pr + (pass << 6);
      if (pix < 900) {
        int qy = pix / 30, qx = pix - qy * 30;
        int cb[2][2], ja_[2][2], jb_[2][2];
        #pragma unroll
        for (int ch = 0; ch < 2; ch++) {
          #pragma unroll
          for (int dy = 0; dy < 2; dy++) {
            unsigned m = (unsigned)(iys[ch] >> (2 * qy + dy)) & 31u;
            int ia = __ffs((int)m) - 1; if (ia < 0) ia = 0;
            int ib = 31 - __clz((int)(m | 1u));
            int cls = m ? (((ib * (ib + 1)) >> 1) + ia + 1) : 0;
            cb[ch][dy] = 122400 + (ch * 16 + cls) * 768 + cgo;
          }
          #pragma unroll
          for (int dx = 0; dx < 2; dx++) {
            unsigned mx = (unsigned)(ixs[ch] >> (2 * qx + dx)) & 31u;
            int ja = __ffs((int)mx) - 1; if (ja < 0) ja = 0;
            int jbp = mx ? (32 - __clz((int)mx)) : 0;
            ja_[ch][dx] = ja * 128; jb_[ch][dx] = jbp * 128;
          }
        }
        float V[8];
        #pragma unroll
        for (int dy = 0; dy < 2; dy++) {
          #pragma unroll
          for (int dx = 0; dx < 2; dx++) {
            float S[8] = {0, 0, 0, 0, 0, 0, 0, 0};
            #pragma unroll
            for (int ch = 0; ch < 2; ch++) {
              uint4 z = *(const uint4*)(smem + cb[ch][dy] + jb_[ch][dx]);
              uint4 a = *(const uint4*)(smem + cb[ch][dy] + ja_[ch][dx]);
              bacc(z, a, S);
            }
            #pragma unroll
            for (int k = 0; k < 8; k++)
              V[k] = (dy == 0 && dx == 0) ? S[k] : fmaxf(V[k], S[k]);
          }
        }
        unsigned dws[4];
        #pragma unroll
        for (int k = 0; k < 4; k++) {
          unsigned lo = (unsigned)f2bf_rne(V[2 * k]     + b1v[2 * k]);
          unsigned hi = (unsigned)f2bf_rne(V[2 * k + 1] + b1v[2 * k + 1]);
          dws[k] = lo | (hi << 16);
        }
        uint2 s0; s0.x = dws[0]; s0.y = dws[1];
        uint2 s1; s1.x = dws[2]; s1.y = dws[3];
        *(uint2*)(smem + pix * 136 + cgo) = s0;
        *(uint2*)(smem + pix * 136 + cgo + 8) = s1;
      }
    }
  }
  __syncthreads();   // Xs complete

  // ---- phase 3: conv2 implicit-GEMM, single pass K=1600 (50 k-steps) ----
  v4f acc[6][2];
  int pclamp[6], baseB[6];
  int cnt = 0;
  #pragma unroll
  for (int it = 0; it < 6; it++) {
    int nt = wv + it * 8;
    if (nt < 43) {
      int p = nt * 16 + ln; if (p > 675) p = 675;   // dup-compute pad lanes
      pclamp[it] = p;
      int y = p / 26, x = p - y * 26;
      baseB[it] = (y * 30 + x) * 136 + q * 16;
      cnt = it + 1;
    } else { pclamp[it] = 0; baseB[it] = 0; }
    acc[it][0] = (v4f)0.f; acc[it][1] = (v4f)0.f;
  }
  const unsigned short* pA0 = Wr + ln * 1600 + q * 8;
  const unsigned short* pA1 = pA0 + 16 * 1600;
  for (int i5 = 0; i5 < 5; i5++) {
    const int ro = i5 * 4080;               // i*30*136
    #pragma unroll
    for (int jt = 0; jt < 5; jt++) {
      #pragma unroll
      for (int hh = 0; hh < 2; hh++) {
        const int s = (i5 * 5 + jt) * 2 + hh;
        v8s a0 = *(const v8s*)(pA0 + s * 32);
        v8s a1 = *(const v8s*)(pA1 + s * 32);
        const int off = ro + jt * 136 + hh * 64;
        #pragma unroll
        for (int it = 0; it < 6; it++) {
          if (it < cnt) {
            uint2 lo = *(const uint2*)(smem + (baseB[it] + off));
            uint2 hi = *(const uint2*)(smem + (baseB[it] + off + 8));
            uint4 bv; bv.x = lo.x; bv.y = lo.y; bv.z = hi.x; bv.w = hi.y;
            v8s b = __builtin_bit_cast(v8s, bv);
            acc[it][0] = __builtin_amdgcn_mfma_f32_16x16x32_bf16(a0, b, acc[it][0], 0, 0, 0);
            acc[it][1] = __builtin_amdgcn_mfma_f32_16x16x32_bf16(a1, b, acc[it][1], 0, 0, 0);
          }
        }
      }
    }
  }

  // ---- phase 4: per m-half, pool2 + mean + bias -> fs[32] ----
  #pragma unroll
  for (int mt = 0; mt < 2; mt++) {
    __syncthreads();               // prior Xs/Cout readers done
    #pragma unroll
    for (int it = 0; it < 6; it++) {
      if (it < cnt) {
        #pragma unroll
        for (int r = 0; r < 4; r++)
          Cout[(q * 4 + r) * 677 + pclamp[it]] = acc[it][mt][r];
      }
    }
    __syncthreads();
    if (t < 208) {
      int c = t & 15, py = t >> 4;
      const float* r0 = Cout + c * 677 + (2 * py) * 26;
      const float* r1 = r0 + 26;
      float s = 0.f;
      #pragma unroll
      for (int px = 0; px < 13; px++) {
        float m0 = fmaxf(r0[2 * px], r0[2 * px + 1]);
        float m1 = fmaxf(r1[2 * px], r1[2 * px + 1]);
        s += fmaxf(m0, m1);
      }
      partial[t] = s;
    }
    __syncthreads();
    if (t < 16) {
      float s = 0.f;
      #pragma unroll
      for (int k = 0; k < 13; k++) s += partial[k * 16 + t];
      fs[mt * 16 + t] = s * (1.f / 169.f) + b2[mt * 16 + t];
    }
  }
  __syncthreads();

  // ---- phase 5: fc (512 outs, thread t -> out column t), relu ----
  {
    const float* wrow = fcw + t * 32;
    float d = 0.f;
    #pragma unroll
    for (int k = 0; k < 32; k++) d += wrow[k] * fs[k];
    out[(u64)n * 512 + t] = fmaxf(d + fcb[t], 0.f);
  }
}

extern "C" void kernel_launch(void* const* d_in, const int* in_sizes, int n_in,
                              void* d_out, int out_size, void* d_ws, size_t ws_size,
                              hipStream_t stream) {
  const float* bboxes = (const float*)d_in[0];
  // d_in[1] = num_obj, d_in[2] = num_relation: constants, unused by the math
  const int*   pairs  = (const int*)  d_in[3];
  const float* w1     = (const float*)d_in[4];
  const float* b1     = (const float*)d_in[5];
  const float* w2     = (const float*)d_in[6];
  const float* b2     = (const float*)d_in[7];
  const float* fcw    = (const float*)d_in[8];
  const float* fcb    = (const float*)d_in[9];
  float* out = (float*)d_out;

  unsigned short* Wr = (unsigned short*)d_ws;                      // 102400 B
  unsigned short* Gt = (unsigned short*)((char*)d_ws + 102400);    //  24576 B

  prepack<<<248, 256, 0, stream>>>(w1, w2, Wr, Gt);
  fused_kernel<<<1024, 512, 147936, stream>>>(bboxes, pairs, Gt, b1, Wr, b2,
                                              fcw, fcb, out);
}

// Round 8
// 236.583 us; speedup vs baseline: 1.7806x; 1.7306x over previous
//
#include <hip/hip_runtime.h>
#include <stdint.h>

typedef unsigned long long u64;
typedef short v8s __attribute__((ext_vector_type(8)));   // 8 bf16 (4 VGPRs) — MFMA A/B frag
typedef float v4f __attribute__((ext_vector_type(4)));   // MFMA C/D frag

__device__ __forceinline__ unsigned short f2bf_rne(float f) {
  union { float f; unsigned u; } c; c.f = f;
  unsigned u = c.u;
  u += 0x7fffu + ((u >> 16) & 1u);   // round-to-nearest-even
  return (unsigned short)(u >> 16);
}

// unpack bf16x8 pair (z,a), accumulate S[k] += z[k] - a[k]
__device__ __forceinline__ void bacc(uint4 z, uint4 a, float* S) {
  const unsigned* zp = &z.x;
  const unsigned* ap = &a.x;
  #pragma unroll
  for (int k = 0; k < 4; k++) {
    unsigned zu = zp[k], au = ap[k];
    S[2 * k]     += __uint_as_float(zu << 16)         - __uint_as_float(au << 16);
    S[2 * k + 1] += __uint_as_float(zu & 0xffff0000u) - __uint_as_float(au & 0xffff0000u);
  }
}

// ============================================================================
// FAST PATH (ws >= 118 MB): two high-occupancy kernels, Xs through HBM.
// ============================================================================

// Kernel A: conv1+pool -> XsG (bf16, xor-swizzled), plus Wr packing.
// Blocks 0..1023: one image each. LDS (39936 B): G-LUT bf16 @0 (24576),
// R f32 build scratch @24576 (15360). 4 blocks/CU, 32 waves/CU.
// XsG layout: img*115200 + h*57600 + pix*64 + ((cg&3 + pix)&3)*16 bytes,
// h = ch-half (cg>>2). The pixel-dependent slot xor makes kernel B's
// contiguous global_load_lds staging land conflict-free for b128 fragments.
// Blocks 1024..1048: pack conv2 weights Wr[h*25600 + c*800 + tap*32 + chh].
__global__ __launch_bounds__(512, 8) void conv1_kernel(
    const float* __restrict__ bboxes,   // [16][32][4]
    const int*   __restrict__ pairs,    // [16][64][2]
    const float* __restrict__ w1,       // [64][2][5][5]
    const float* __restrict__ b1,       // [64]
    const float* __restrict__ w2,       // [32][64][5][5]
    unsigned short* __restrict__ XsG,   // [1024][2][900][32] swizzled bf16
    unsigned short* __restrict__ Wr)    // [2][32][800] bf16
{
  const int t = threadIdx.x;
  if (blockIdx.x >= 1024) {             // Wr-pack blocks
    int bb2 = blockIdx.x - 1024;
    #pragma unroll
    for (int r = 0; r < 4; r++) {
      int idx = bb2 * 2048 + r * 512 + t;   // < 51200
      int c = idx / 1600, rem = idx - c * 1600;
      int h = rem / 800, r2 = rem - h * 800;
      int tap = r2 >> 5, chh = r2 & 31;
      Wr[h * 25600 + c * 800 + r2] =
          f2bf_rne(w2[(c * 64 + h * 32 + chh) * 25 + tap]);
    }
    return;
  }
  extern __shared__ char smem[];
  unsigned short* Gs = (unsigned short*)smem;
  float* R = (float*)(smem + 24576);

  const int n = blockIdx.x;
  const int lane = t & 63;

  // ---- G-LUT build: R[ch][i][j6][cout] = col-prefix of w1 row i ----
  for (int rid = t; rid < 640; rid += 512) {
    int ch = rid / 320, rr = rid - ch * 320;
    int i = rr >> 6, cout = rr & 63;
    const float* wp = w1 + (cout * 2 + ch) * 25 + i * 5;
    float* Rp = R + (ch * 5 + i) * 384 + cout;
    float s = 0.f;
    #pragma unroll
    for (int j = 0; j < 5; j++) { Rp[j * 64] = s; s += wp[j]; }
    Rp[5 * 64] = s;
  }
  __syncthreads();
  // G[ch][cls16][j6][cout64]: cls=(ia,ib) row-run; G = sum_{i=ia..ib} R[i]
  for (int e = t; e < 12288; e += 512) {
    int ch = e / 6144, r = e - ch * 6144;
    int cls = r / 384, r2 = r - cls * 384;
    float v = 0.f;
    if (cls > 0) {
      int ia = 0, ib = 0;
      #pragma unroll
      for (int bb2 = 0; bb2 < 5; bb2++) {
        int base = (bb2 * (bb2 + 1)) / 2 + 1;
        if (cls >= base) { ib = bb2; ia = cls - base; }
      }
      const float* Rp = R + ch * 1920 + r2;
      for (int i = ia; i <= ib; i++) v += Rp[i * 384];
    }
    Gs[e] = f2bf_rne(v);
  }

  // ---- box pair -> indicator bitmasks (lane = coordinate) ----
  const int bb = n >> 6, rr_ = n & 63;
  const int p0 = pairs[(bb * 64 + rr_) * 2 + 0];
  const int p1 = pairs[(bb * 64 + rr_) * 2 + 1];
  const float* A  = bboxes + (bb * 32 + p0) * 4;
  const float* Bq = bboxes + (bb * 32 + p1) * 4;
  const float ax1 = A[0],  ay1 = A[1],  ax2 = A[2],  ay2 = A[3];
  const float cx1 = Bq[0], cy1 = Bq[1], cx2 = Bq[2], cy2 = Bq[3];
  const float ux1 = fminf(ax1, cx1), uy1 = fminf(ay1, cy1);
  const float ux2 = fmaxf(ax2, cx2), uy2 = fmaxf(ay2, cy2);
  const float uw = fmaxf(ux2 - ux1, 1e-6f), uh = fmaxf(uy2 - uy1, 1e-6f);
  const float g = (float)lane + 0.5f;
  u64 ixs[2], iys[2];
  {
    float X1 = (ax1 - ux1) / uw * 64.f, X2 = (ax2 - ux1) / uw * 64.f;
    float Y1 = (ay1 - uy1) / uh * 64.f, Y2 = (ay2 - uy1) / uh * 64.f;
    ixs[0] = __ballot(g >= X1 && g <= X2);
    iys[0] = __ballot(g >= Y1 && g <= Y2);
  }
  {
    float X1 = (cx1 - ux1) / uw * 64.f, X2 = (cx2 - ux1) / uw * 64.f;
    float Y1 = (cy1 - uy1) / uh * 64.f, Y2 = (cy2 - uy1) / uh * 64.f;
    ixs[1] = __ballot(g >= X1 && g <= X2);
    iys[1] = __ballot(g >= Y1 && g <= Y2);
  }
  __syncthreads();   // G resident

  // ---- conv1+pool sweep: item = (pixel, cout-group), barrier-free ----
  const int cg = t & 7, cgo = cg * 16, pr = t >> 3;
  const int hW = cg >> 2;
  float b1v[8];
  #pragma unroll
  for (int i = 0; i < 8; i++) b1v[i] = b1[cg * 8 + i];
  char* const Xbase = (char*)XsG + (u64)n * 115200 + hW * 57600;
  for (int pass = 0; pass < 15; pass++) {
    int pix = pr + (pass << 6);
    if (pix < 900) {
      int qy = pix / 30, qx = pix - qy * 30;
      int cb[2][2], ja_[2][2], jb_[2][2];
      #pragma unroll
      for (int ch = 0; ch < 2; ch++) {
        #pragma unroll
        for (int dy = 0; dy < 2; dy++) {
          unsigned m = (unsigned)(iys[ch] >> (2 * qy + dy)) & 31u;
          int ia = __ffs((int)m) - 1; if (ia < 0) ia = 0;
          int ib = 31 - __clz((int)(m | 1u));
          int cls = m ? (((ib * (ib + 1)) >> 1) + ia + 1) : 0;
          cb[ch][dy] = (ch * 16 + cls) * 768 + cgo;
        }
        #pragma unroll
        for (int dx = 0; dx < 2; dx++) {
          unsigned mx = (unsigned)(ixs[ch] >> (2 * qx + dx)) & 31u;
          int ja = __ffs((int)mx) - 1; if (ja < 0) ja = 0;
          int jbp = mx ? (32 - __clz((int)mx)) : 0;
          ja_[ch][dx] = ja * 128; jb_[ch][dx] = jbp * 128;
        }
      }
      float V[8];
      #pragma unroll
      for (int dy = 0; dy < 2; dy++) {
        #pragma unroll
        for (int dx = 0; dx < 2; dx++) {
          float S[8] = {0, 0, 0, 0, 0, 0, 0, 0};
          #pragma unroll
          for (int ch = 0; ch < 2; ch++) {
            uint4 z = *(const uint4*)(smem + cb[ch][dy] + jb_[ch][dx]);
            uint4 a = *(const uint4*)(smem + cb[ch][dy] + ja_[ch][dx]);
            bacc(z, a, S);
          }
          #pragma unroll
          for (int k = 0; k < 8; k++)
            V[k] = (dy == 0 && dx == 0) ? S[k] : fmaxf(V[k], S[k]);
        }
      }
      uint4 pk;
      unsigned* pkp = &pk.x;
      #pragma unroll
      for (int k = 0; k < 4; k++) {
        unsigned lo = (unsigned)f2bf_rne(V[2 * k]     + b1v[2 * k]);
        unsigned hi = (unsigned)f2bf_rne(V[2 * k + 1] + b1v[2 * k + 1]);
        pkp[k] = lo | (hi << 16);
      }
      int slot = ((cg & 3) + pix) & 3;
      *(uint4*)(Xbase + pix * 64 + slot * 16) = pk;
    }
  }
}

// Kernel B: conv2 implicit-GEMM + pool + mean + fc. One block/image.
// LDS 58560 B -> 2 blocks/CU: Xs half @0 (57600, staged via global_load_lds
// width-16), partial @57600, fs @58432; Cout (16x677 f32 = 43328) aliases Xs.
// b128 fragment read: addr = ps*64 + ((q+ps)&3)*16 -> uniform bank spread.
__global__ __launch_bounds__(512, 4) void conv2_kernel(
    const unsigned short* __restrict__ XsG,
    const unsigned short* __restrict__ Wr,   // [2][32][800] bf16
    const float* __restrict__ b2,            // [32]
    const float* __restrict__ fcw,           // [512][32]
    const float* __restrict__ fcb,           // [512]
    float* __restrict__ out)                 // [1024][512]
{
  extern __shared__ char smem[];
  float* partial = (float*)(smem + 57600);
  float* fs      = (float*)(smem + 58432);
  float* Cout    = (float*)smem;

  const int n = blockIdx.x, t = threadIdx.x;
  const int lane = t & 63, wv = t >> 6;
  const int q = lane >> 4, ln = lane & 15;

  // n-tiles of 16 pixels, 43 tiles over 676 outputs
  v4f acc[6][2];
  int pclamp[6], psB[6];
  int cnt = 0;
  #pragma unroll
  for (int it = 0; it < 6; it++) {
    int nt = wv + it * 8;
    if (nt < 43) {
      int p = nt * 16 + ln; if (p > 675) p = 675;   // dup-compute pad lanes
      pclamp[it] = p;
      int y = p / 26, x = p - y * 26;
      psB[it] = y * 30 + x;
      cnt = it + 1;
    } else { pclamp[it] = 0; psB[it] = 0; }
    acc[it][0] = (v4f)0.f; acc[it][1] = (v4f)0.f;
  }

  const char* Xg = (const char*)XsG + (u64)n * 115200;
  for (int h = 0; h < 2; h++) {
    if (h) __syncthreads();            // all h=0 fragment reads done
    // stage 57600 B = 3600 16-B chunks, direct global->LDS
    {
      const char* src = Xg + h * 57600;
      #pragma unroll
      for (int k = 0; k < 7; k++) {
        int ci = k * 512 + t;
        __builtin_amdgcn_global_load_lds(
            (const __attribute__((address_space(1))) unsigned int*)(src + ci * 16),
            (__attribute__((address_space(3))) unsigned int*)(smem + ci * 16),
            16, 0, 0);
      }
      if (t < 16) {
        int ci = 3584 + t;
        __builtin_amdgcn_global_load_lds(
            (const __attribute__((address_space(1))) unsigned int*)(src + ci * 16),
            (__attribute__((address_space(3))) unsigned int*)(smem + ci * 16),
            16, 0, 0);
      }
    }
    __syncthreads();                   // staging drained (vmcnt before barrier)

    const unsigned short* pA0 = Wr + h * 25600 + ln * 800 + q * 8;
    const unsigned short* pA1 = pA0 + 16 * 800;
    for (int i = 0; i < 5; i++) {      // filter row
      #pragma unroll
      for (int j = 0; j < 5; j++) {    // filter col; tap covers 32 ch = one MFMA k-step
        const int tap = i * 5 + j;
        v8s a0 = *(const v8s*)(pA0 + tap * 32);
        v8s a1 = *(const v8s*)(pA1 + tap * 32);
        #pragma unroll
        for (int it = 0; it < 6; it++) {
          if (it < cnt) {
            int ps = psB[it] + i * 30 + j;
            int addr = (ps << 6) + (((q + ps) & 3) << 4);
            v8s b = *(const v8s*)(smem + addr);
            acc[it][0] = __builtin_amdgcn_mfma_f32_16x16x32_bf16(a0, b, acc[it][0], 0, 0, 0);
            acc[it][1] = __builtin_amdgcn_mfma_f32_16x16x32_bf16(a1, b, acc[it][1], 0, 0, 0);
          }
        }
      }
    }
  }

  // ---- per m-half, pool2 + mean + bias -> fs[32] ----
  #pragma unroll
  for (int mt = 0; mt < 2; mt++) {
    __syncthreads();               // prior Xs/Cout readers done
    #pragma unroll
    for (int it = 0; it < 6; it++) {
      if (it < cnt) {
        #pragma unroll
        for (int r = 0; r < 4; r++)
          Cout[(q * 4 + r) * 677 + pclamp[it]] = acc[it][mt][r];
      }
    }
    __syncthreads();
    if (t < 208) {
      int c = t & 15, py = t >> 4;
      const float* r0 = Cout + c * 677 + (2 * py) * 26;
      const float* r1 = r0 + 26;
      float s = 0.f;
      #pragma unroll
      for (int px = 0; px < 13; px++) {
        float m0 = fmaxf(r0[2 * px], r0[2 * px + 1]);
        float m1 = fmaxf(r1[2 * px], r1[2 * px + 1]);
        s += fmaxf(m0, m1);
      }
      partial[t] = s;
    }
    __syncthreads();
    if (t < 16) {
      float s = 0.f;
      #pragma unroll
      for (int k = 0; k < 13; k++) s += partial[k * 16 + t];
      fs[mt * 16 + t] = s * (1.f / 169.f) + b2[mt * 16 + t];
    }
  }
  __syncthreads();

  // ---- fc (512 outs, thread t -> out column t), relu ----
  {
    const float* wrow = fcw + t * 32;
    float d = 0.f;
    #pragma unroll
    for (int k = 0; k < 32; k++) d += wrow[k] * fs[k];
    out[(u64)n * 512 + t] = fmaxf(d + fcb[t], 0.f);
  }
}

// ============================================================================
// FALLBACK PATH (small ws): round-7 fused kernel, 409 us.
// ============================================================================

__global__ __launch_bounds__(256) void prepack(
    const float* __restrict__ w1, const float* __restrict__ w2,
    unsigned short* __restrict__ Wr, unsigned short* __restrict__ Gt) {
  int idx = blockIdx.x * 256 + threadIdx.x;
  if (idx < 51200) {
    int c = idx / 1600, rem = idx - c * 1600;
    int ch = rem & 63, tap = rem >> 6;
    Wr[idx] = f2bf_rne(w2[(c * 64 + ch) * 25 + tap]);
  } else if (idx < 51200 + 12288) {
    int e = idx - 51200;
    int ch = e / 6144, r = e - ch * 6144;
    int cls = r / 384, r2 = r - cls * 384;
    int j = r2 / 64, cout = r2 - j * 64;
    float v = 0.f;
    if (cls > 0) {
      int ia = 0, ib = 0;
      for (int bb = 0; bb < 5; bb++) {
        int base = (bb * (bb + 1)) / 2 + 1;
        if (cls >= base && cls <= base + bb) { ib = bb; ia = cls - base; }
      }
      for (int i = ia; i <= ib; i++)
        for (int jj = 0; jj < j; jj++)
          v += w1[(cout * 2 + ch) * 25 + i * 5 + jj];
    }
    Gt[e] = f2bf_rne(v);
  }
}

__global__ __launch_bounds__(512, 2) void fused_kernel(
    const float* __restrict__ bboxes, const int* __restrict__ pairs,
    const unsigned short* __restrict__ Gt, const float* __restrict__ b1,
    const unsigned short* __restrict__ Wr, const float* __restrict__ b2,
    const float* __restrict__ fcw, const float* __restrict__ fcb,
    float* __restrict__ out)
{
  extern __shared__ char smem[];
  float* partial = (float*)(smem + 146976);
  float* fs      = (float*)(smem + 147808);
  float* Cout    = (float*)smem;

  const int n = blockIdx.x, t = threadIdx.x;
  const int lane = t & 63, wv = t >> 6;
  const int q = lane >> 4, ln = lane & 15;

  {
    const uint4* src = (const uint4*)Gt;
    uint4* dst = (uint4*)(smem + 122400);
    #pragma unroll
    for (int i = 0; i < 3; i++) dst[t + i * 512] = src[t + i * 512];
  }
  const int bb = n >> 6, rr_ = n & 63;
  const int p0 = pairs[(bb * 64 + rr_) * 2 + 0];
  const int p1 = pairs[(bb * 64 + rr_) * 2 + 1];
  const float* A  = bboxes + (bb * 32 + p0) * 4;
  const float* Bq = bboxes + (bb * 32 + p1) * 4;
  const float ax1 = A[0],  ay1 = A[1],  ax2 = A[2],  ay2 = A[3];
  const float cx1 = Bq[0], cy1 = Bq[1], cx2 = Bq[2], cy2 = Bq[3];
  const float ux1 = fminf(ax1, cx1), uy1 = fminf(ay1, cy1);
  const float ux2 = fmaxf(ax2, cx2), uy2 = fmaxf(ay2, cy2);
  const float uw = fmaxf(ux2 - ux1, 1e-6f), uh = fmaxf(uy2 - uy1, 1e-6f);
  const float g = (float)lane + 0.5f;
  u64 ixs[2], iys[2];
  {
    float X1 = (ax1 - ux1) / uw * 64.f, X2 = (ax2 - ux1) / uw * 64.f;
    float Y1 = (ay1 - uy1) / uh * 64.f, Y2 = (ay2 - uy1) / uh * 64.f;
    ixs[0] = __ballot(g >= X1 && g <= X2);
    iys[0] = __ballot(g >= Y1 && g <= Y2);
  }
  {
    float X1 = (cx1 - ux1) / uw * 64.f, X2 = (cx2 - ux1) / uw * 64.f;
    float Y1 = (cy1 - uy1) / uh * 64.f, Y2 = (cy2 - uy1) / uh * 64.f;
    ixs[1] = __ballot(g >= X1 && g <= X2);
    iys[1] = __ballot(g >= Y1 && g <= Y2);
  }
  __syncthreads();

  {
    const int cg = t & 7, cgo = cg * 16, pr = t >> 3;
    float b1v[8];
    #pragma unroll
    for (int i = 0; i < 8; i++) b1v[i] = b1[cg * 8 + i];
    for (int pass = 0; pass < 15; pass++) {
      int pix = pr + (pass << 6);
      if (pix < 900) {
        int qy = pix / 30, qx = pix - qy * 30;
        int cb[2][2], ja_[2][2], jb_[2][2];
        #pragma unroll
        for (int ch = 0; ch < 2; ch++) {
          #pragma unroll
          for (int dy = 0; dy < 2; dy++) {
            unsigned m = (unsigned)(iys[ch] >> (2 * qy + dy)) & 31u;
            int ia = __ffs((int)m) - 1; if (ia < 0) ia = 0;
            int ib = 31 - __clz((int)(m | 1u));
            int cls = m ? (((ib * (ib + 1)) >> 1) + ia + 1) : 0;
            cb[ch][dy] = 122400 + (ch * 16 + cls) * 768 + cgo;
          }
          #pragma unroll
          for (int dx = 0; dx < 2; dx++) {
            unsigned mx = (unsigned)(ixs[ch] >> (2 * qx + dx)) & 31u;
            int ja = __ffs((int)mx) - 1; if (ja < 0) ja = 0;
            int jbp = mx ? (32 - __clz((int)mx)) : 0;
            ja_[ch][dx] = ja * 128; jb_[ch][dx] = jbp * 128;
          }
        }
        float V[8];
        #pragma unroll
        for (int dy = 0; dy < 2; dy++) {
          #pragma unroll
          for (int dx = 0; dx < 2; dx++) {
            float S[8] = {0, 0, 0, 0, 0, 0, 0, 0};
            #pragma unroll
            for (int ch = 0; ch < 2; ch++) {
              uint4 z = *(const uint4*)(smem + cb[ch][dy] + jb_[ch][dx]);
              uint4 a = *(const uint4*)(smem + cb[ch][dy] + ja_[ch][dx]);
              bacc(z, a, S);
            }
            #pragma unroll
            for (int k = 0; k < 8; k++)
              V[k] = (dy == 0 && dx == 0) ? S[k] : fmaxf(V[k], S[k]);
          }
        }
        unsigned dws[4];
        #pragma unroll
        for (int k = 0; k < 4; k++) {
          unsigned lo = (unsigned)f2bf_rne(V[2 * k]     + b1v[2 * k]);
          unsigned hi = (unsigned)f2bf_rne(V[2 * k + 1] + b1v[2 * k + 1]);
          dws[k] = lo | (hi << 16);
        }
        uint2 s0; s0.x = dws[0]; s0.y = dws[1];
        uint2 s1; s1.x = dws[2]; s1.y = dws[3];
        *(uint2*)(smem + pix * 136 + cgo) = s0;
        *(uint2*)(smem + pix * 136 + cgo + 8) = s1;
      }
    }
  }
  __syncthreads();

  v4f acc[6][2];
  int pclamp[6], baseB[6];
  int cnt = 0;
  #pragma unroll
  for (int it = 0; it < 6; it++) {
    int nt = wv + it * 8;
    if (nt < 43) {
      int p = nt * 16 + ln; if (p > 675) p = 675;
      pclamp[it] = p;
      int y = p / 26, x = p - y * 26;
      baseB[it] = (y * 30 + x) * 136 + q * 16;
      cnt = it + 1;
    } else { pclamp[it] = 0; baseB[it] = 0; }
    acc[it][0] = (v4f)0.f; acc[it][1] = (v4f)0.f;
  }
  const unsigned short* pA0 = Wr + ln * 1600 + q * 8;
  const unsigned short* pA1 = pA0 + 16 * 1600;
  for (int i5 = 0; i5 < 5; i5++) {
    const int ro = i5 * 4080;
    #pragma unroll
    for (int jt = 0; jt < 5; jt++) {
      #pragma unroll
      for (int hh = 0; hh < 2; hh++) {
        const int s = (i5 * 5 + jt) * 2 + hh;
        v8s a0 = *(const v8s*)(pA0 + s * 32);
        v8s a1 = *(const v8s*)(pA1 + s * 32);
        const int off = ro + jt * 136 + hh * 64;
        #pragma unroll
        for (int it = 0; it < 6; it++) {
          if (it < cnt) {
            uint2 lo = *(const uint2*)(smem + (baseB[it] + off));
            uint2 hi = *(const uint2*)(smem + (baseB[it] + off + 8));
            uint4 bv; bv.x = lo.x; bv.y = lo.y; bv.z = hi.x; bv.w = hi.y;
            v8s b = __builtin_bit_cast(v8s, bv);
            acc[it][0] = __builtin_amdgcn_mfma_f32_16x16x32_bf16(a0, b, acc[it][0], 0, 0, 0);
            acc[it][1] = __builtin_amdgcn_mfma_f32_16x16x32_bf16(a1, b, acc[it][1], 0, 0, 0);
          }
        }
      }
    }
  }
  #pragma unroll
  for (int mt = 0; mt < 2; mt++) {
    __syncthreads();
    #pragma unroll
    for (int it = 0; it < 6; it++) {
      if (it < cnt) {
        #pragma unroll
        for (int r = 0; r < 4; r++)
          Cout[(q * 4 + r) * 677 + pclamp[it]] = acc[it][mt][r];
      }
    }
    __syncthreads();
    if (t < 208) {
      int c = t & 15, py = t >> 4;
      const float* r0 = Cout + c * 677 + (2 * py) * 26;
      const float* r1 = r0 + 26;
      float s = 0.f;
      #pragma unroll
      for (int px = 0; px < 13; px++) {
        float m0 = fmaxf(r0[2 * px], r0[2 * px + 1]);
        float m1 = fmaxf(r1[2 * px], r1[2 * px + 1]);
        s += fmaxf(m0, m1);
      }
      partial[t] = s;
    }
    __syncthreads();
    if (t < 16) {
      float s = 0.f;
      #pragma unroll
      for (int k = 0; k < 13; k++) s += partial[k * 16 + t];
      fs[mt * 16 + t] = s * (1.f / 169.f) + b2[mt * 16 + t];
    }
  }
  __syncthreads();
  {
    const float* wrow = fcw + t * 32;
    float d = 0.f;
    #pragma unroll
    for (int k = 0; k < 32; k++) d += wrow[k] * fs[k];
    out[(u64)n * 512 + t] = fmaxf(d + fcb[t], 0.f);
  }
}

extern "C" void kernel_launch(void* const* d_in, const int* in_sizes, int n_in,
                              void* d_out, int out_size, void* d_ws, size_t ws_size,
                              hipStream_t stream) {
  const float* bboxes = (const float*)d_in[0];
  // d_in[1] = num_obj, d_in[2] = num_relation: constants, unused by the math
  const int*   pairs  = (const int*)  d_in[3];
  const float* w1     = (const float*)d_in[4];
  const float* b1     = (const float*)d_in[5];
  const float* w2     = (const float*)d_in[6];
  const float* b2     = (const float*)d_in[7];
  const float* fcw    = (const float*)d_in[8];
  const float* fcb    = (const float*)d_in[9];
  float* out = (float*)d_out;

  const u64 xs_bytes = (u64)1024 * 115200;
  if (ws_size >= xs_bytes + 102400) {
    // fast path: conv1 -> HBM (swizzled) -> conv2 staged via global_load_lds
    unsigned short* XsG = (unsigned short*)d_ws;
    unsigned short* Wr  = (unsigned short*)((char*)d_ws + xs_bytes);
    conv1_kernel<<<1049, 512, 39936, stream>>>(bboxes, pairs, w1, b1, w2, XsG, Wr);
    conv2_kernel<<<1024, 512, 58560, stream>>>(XsG, Wr, b2, fcw, fcb, out);
  } else {
    // fallback: round-7 fused path
    unsigned short* Wr = (unsigned short*)d_ws;                      // 102400 B
    unsigned short* Gt = (unsigned short*)((char*)d_ws + 102400);    //  24576 B
    prepack<<<248, 256, 0, stream>>>(w1, w2, Wr, Gt);
    fused_kernel<<<1024, 512, 147936, stream>>>(bboxes, pairs, Gt, b1, Wr, b2,
                                                fcw, fcb, out);
  }
}